// Round 7
// baseline (164.931 us; speedup 1.0000x reference)
//
#include <hip/hip_runtime.h>

#define BB 16
#define TT 8192
#define NN 128                     // N_PRE == N_POST
constexpr int CHUNK = 256;         // time-steps per block
constexpr int NBLK  = BB * TT / CHUNK;   // 512 blocks
constexpr int OUTN  = NN * NN;           // 16384
constexpr int GS    = 264;         // g_lds row stride in halves (528 B rows, 16B-aligned)
constexpr int SLOTS = OUTN / 2;    // 8192 packed u32 slots per k-slice
constexpr int PROWS = 315;         // staged post rows: (t0, t0+315]

typedef _Float16 f16x8 __attribute__((ext_vector_type(8)));
typedef _Float16 f16x2 __attribute__((ext_vector_type(2)));
typedef float    f32x4 __attribute__((ext_vector_type(4)));

__device__ __forceinline__ unsigned short h16(float x) {
    _Float16 h = (_Float16)x;
    return __builtin_bit_cast(unsigned short, h);
}
__device__ __forceinline__ unsigned int pack2(float x, float y) {
    return (unsigned int)h16(x) | ((unsigned int)h16(y) << 16);
}
__device__ __forceinline__ float2 ldL(const unsigned short* p_lds, int m, int q0) {
    const unsigned int v = *(const unsigned int*)&p_lds[m * NN + q0];
    const f16x2 h = __builtin_bit_cast(f16x2, v);
    return make_float2((float)h[0], (float)h[1]);
}

// grid 512 x 512 threads. Block = one 256-step chunk of one batch.
// Phase 0: stage post rows (t0, t0+315] as f16 into LDS — two explicit
//          register batches (10 float4 each) to force MLP.
// Phase 1: wave wv filters 32-step window wv from LDS (2 q per lane) into regs.
// Phase 2: dump g over the post region; ps write; MFMA over K=256.
template<bool ATOMIC>
__global__ __launch_bounds__(512, 4)
void stdp_main(const float* __restrict__ pre, const float* __restrict__ post,
               const int* __restrict__ dtp,
               unsigned int* __restrict__ part, float* __restrict__ wpost,
               float* __restrict__ outat)
{
    __shared__ __align__(16) char smem[PROWS * NN * 2];      // 80,640 B
    unsigned short* post_lds = (unsigned short*)smem;        // [315][128] f16
    unsigned short* g_lds    = (unsigned short*)smem;        // [128][264] f16 (phase 2)
    float*          lds_ps   = (float*)(smem + NN * GS * 2); // [8][128] (phase 2)

    const int tid   = threadIdx.x;
    const int blk   = blockIdx.x;
    const int b     = blk >> 5;          // 16 batches
    const int chunk = blk & 31;          // 32 chunks per batch
    const int t0    = chunk * CHUNK;
    const int wv    = tid >> 6;          // wave 0..7
    const int lane  = tid & 63;

    const float dtf = (float)(*dtp);
    const float r   = expf(-dtf * (1.0f / 20.0f));

    const float* pb = post + (size_t)b * TT * NN;
    const float* ab = pre  + (size_t)b * TT * NN;

    // ---------- phase 0: stage post tile, 2 register batches for MLP ----------
    {
        const int c  = tid & 31;         // float4 column within row
        const int mr = tid >> 5;         // starting row (0..15)
        float4 va[10];
        // batch 1: rows mr + {0,16,...,144} — always < 315
        #pragma unroll
        for (int i = 0; i < 10; ++i) {
            const int t = t0 + 1 + mr + i * 16;
            va[i] = (t < TT) ? *(const float4*)(pb + (size_t)t * NN + c * 4)
                             : make_float4(0.f, 0.f, 0.f, 0.f);
        }
        #pragma unroll
        for (int i = 0; i < 10; ++i) {
            const int m = mr + i * 16;
            *(uint2*)&post_lds[m * NN + c * 4] =
                make_uint2(pack2(va[i].x, va[i].y), pack2(va[i].z, va[i].w));
        }
        // batch 2: rows mr + {160,...,304} — guard m < 315
        #pragma unroll
        for (int i = 0; i < 10; ++i) {
            const int m = mr + (i + 10) * 16;
            const int t = t0 + 1 + m;
            va[i] = (m < PROWS && t < TT) ? *(const float4*)(pb + (size_t)t * NN + c * 4)
                                          : make_float4(0.f, 0.f, 0.f, 0.f);
        }
        #pragma unroll
        for (int i = 0; i < 10; ++i) {
            const int m = mr + (i + 10) * 16;
            if (m < PROWS)
                *(uint2*)&post_lds[m * NN + c * 4] =
                    make_uint2(pack2(va[i].x, va[i].y), pack2(va[i].z, va[i].w));
        }
    }
    __syncthreads();

    // ---------- phase 1: filter window wv (32 steps), 2 q per lane ----------
    const int win  = wv;
    const int q0   = lane * 2;
    const int base = win * 32;           // local row base: P[ts+k] -> row base+k-1
    float ps0 = 0.f, ps1 = 0.f;          // post sums over (ts, ts+32]

    unsigned int pk0[16], pk1[16];       // 32 f16 steps per q
    {
        float2 p  = ldL(post_lds, base + 31, q0);   // tau=1: P[ts+32]
        float wt  = r;
        float gx = r * p.x, gy = r * p.y;
        ps0 += p.x; ps1 += p.y;
        #pragma unroll
        for (int tau = 2; tau <= 59; ++tau) {
            wt *= r;
            p = ldL(post_lds, base + 30 + tau, q0);
            gx = fmaf(wt, p.x, gx);
            gy = fmaf(wt, p.y, gy);
        }
        const float r60 = wt * r;        // r^60, consistent with chained weights
        pk0[15] = (unsigned int)h16(gx) << 16;   // step 31 = high half of word 15
        pk1[15] = (unsigned int)h16(gy) << 16;
        // recurrence downward: g[t] = r*(g[t+1]+P(t+1)) - r^60*P(t+60)
        #pragma unroll
        for (int c = 30; c >= 0; --c) {
            const float2 p1  = ldL(post_lds, base + c,      q0);  // P[ts+c+1]
            const float2 p60 = ldL(post_lds, base + c + 59, q0);  // P[ts+c+60]
            gx = r * (gx + p1.x) - r60 * p60.x;
            gy = r * (gy + p1.y) - r60 * p60.y;
            ps0 += p1.x; ps1 += p1.y;
            if (c & 1) {
                pk0[c >> 1] = (unsigned int)h16(gx) << 16;
                pk1[c >> 1] = (unsigned int)h16(gy) << 16;
            } else {
                pk0[c >> 1] |= h16(gx);
                pk1[c >> 1] |= h16(gy);
            }
        }
    }
    __syncthreads();                     // all post_lds reads done before overwrite

    // ---------- phase 2a: dump g over the post region; stash ps ----------
    {
        unsigned short* d0 = &g_lds[q0 * GS + win * 32];
        unsigned short* d1 = &g_lds[(q0 + 1) * GS + win * 32];
        #pragma unroll
        for (int s = 0; s < 4; ++s) {
            *(uint4*)(d0 + 8 * s) = make_uint4(pk0[4*s], pk0[4*s+1], pk0[4*s+2], pk0[4*s+3]);
            *(uint4*)(d1 + 8 * s) = make_uint4(pk1[4*s], pk1[4*s+1], pk1[4*s+2], pk1[4*s+3]);
        }
        lds_ps[win * NN + q0]     = ps0;
        lds_ps[win * NN + q0 + 1] = ps1;
    }
    __syncthreads();

    // ---------- post column sums (data valid as of the sync above) ----------
    if (tid < NN) {
        float s = 0.f;
        #pragma unroll
        for (int w = 0; w < 8; ++w) s += lds_ps[w * NN + tid];
        if (chunk == 0) s += pb[tid];    // window (t0,t0+256] misses t=0 row once per batch
        if constexpr (ATOMIC) atomicAdd(&wpost[tid], s);
        else wpost[(size_t)tid * NBLK + blk] = s;   // [q][NBLK] for coalesced reduce
    }

    // ---------- phase 2b: MFMA S[p,q] += pre^T @ g, K=256 ----------
    const int pr0 = wv * 16;
    f32x4 acc[8];
    #pragma unroll
    for (int qt = 0; qt < 8; ++qt) acc[qt] = (f32x4){0.f, 0.f, 0.f, 0.f};

    const float* abase = ab + (size_t)(t0 + (lane >> 4) * 8) * NN + pr0 + (lane & 15);
    float an[8];
    #pragma unroll
    for (int j = 0; j < 8; ++j) an[j] = abase[(size_t)j * NN];      // ks=0 raw f32

    #pragma unroll
    for (int ks = 0; ks < 8; ++ks) {
        f16x8 af;
        #pragma unroll
        for (int j = 0; j < 8; ++j) af[j] = (_Float16)an[j];        // 0/1 exact in fp16
        if (ks < 7) {
            const float* src = abase + (size_t)((ks + 1) * 32) * NN;
            #pragma unroll
            for (int j = 0; j < 8; ++j) an[j] = src[(size_t)j * NN]; // prefetch ks+1
        }
        const int koff = ks * 32 + (lane >> 4) * 8;
        #pragma unroll
        for (int qt = 0; qt < 8; ++qt) {
            const f16x8 bf = *(const f16x8*)&g_lds[(qt * 16 + (lane & 15)) * GS + koff];
            acc[qt] = __builtin_amdgcn_mfma_f32_16x16x32_f16(af, bf, acc[qt], 0, 0, 0);
        }
    }

    // ---------- write partial S: u32-packed f16 pairs, 256B/instr coalesced ----------
    if constexpr (!ATOMIC) {
        unsigned int* dst = part + ((size_t)blk * 8 + wv) * 1024 + lane;  // 8 qt * 2 rgpair * 64
        #pragma unroll
        for (int qt = 0; qt < 8; ++qt)
            #pragma unroll
            for (int rp = 0; rp < 2; ++rp)
                dst[qt * 128 + rp * 64] = pack2(acc[qt][2 * rp], acc[qt][2 * rp + 1]);
    } else {
        #pragma unroll
        for (int qt = 0; qt < 8; ++qt)
            #pragma unroll
            for (int rg = 0; rg < 4; ++rg) {
                const int prow = pr0 + (lane >> 4) * 4 + rg;
                const int qcol = qt * 16 + (lane & 15);
                atomicAdd(&outat[prow * NN + qcol], acc[qt][rg]);
            }
    }
}

// 128 blocks x 64 threads: block q reduces its NBLK partial sums (coalesced), shfl tree.
__global__ void hfac_kernel(const float* __restrict__ wpost, const int* __restrict__ dtp,
                            float* __restrict__ hfac, int nb)
{
    const int q = blockIdx.x;
    float s = 0.f;
    for (int k = threadIdx.x; k < nb; k += 64) s += wpost[(size_t)q * nb + k];
    #pragma unroll
    for (int off = 32; off; off >>= 1) s += __shfl_down(s, off, 64);
    if (threadIdx.x == 0) {
        const float dtf   = (float)(*dtp);
        const float alpha = dtf * 1e-3f;
        const float mean  = s * (1.0f / (float)(BB * TT));
        hfac[q] = -0.001f * (alpha * (mean - 0.1f));
    }
}

// fused split-K reduce + epilogue: 128 blocks x 512 thr, 8-way k-split,
// 256B/instr coalesced part reads; un-permute + homeostatic epilogue.
__global__ __launch_bounds__(512)
void finalize_ws(const unsigned int* __restrict__ part, const float* __restrict__ hfac,
                 const float* __restrict__ W, float* __restrict__ out)
{
    __shared__ float2 red[512];
    const int s    = threadIdx.x & 63;        // slot within block's 64
    const int kq   = threadIdx.x >> 6;        // 0..7
    const int slot = blockIdx.x * 64 + s;     // 0..8191
    float sx = 0.f, sy = 0.f;
    #pragma unroll 8
    for (int k = kq * 64; k < kq * 64 + 64; ++k) {
        const unsigned int v = part[(size_t)k * SLOTS + slot];
        const f16x2 h = __builtin_bit_cast(f16x2, v);
        sx += (float)h[0];
        sy += (float)h[1];
    }
    red[threadIdx.x] = make_float2(sx, sy);
    __syncthreads();
    if (threadIdx.x < 64) {
        float tx = red[s].x, ty = red[s].y;   // own kq=0 partial
        #pragma unroll
        for (int g = 1; g < 8; ++g) {
            const float2 v = red[g * 64 + s];
            tx += v.x; ty += v.y;
        }
        // un-permute slot -> (p, q)
        const int lane = slot & 63;
        const int rp   = (slot >> 6) & 1;
        const int qt   = (slot >> 7) & 7;
        const int wv   = slot >> 10;
        const int p    = wv * 16 + ((lane >> 4) << 2) + rp * 2;
        const int q    = qt * 16 + (lane & 15);
        const float scale = (float)((0.005 - 0.00525) / (double)(BB * TT));
        const float hf = hfac[q];
        out[p * NN + q]       = fmaf(tx, scale, hf * W[p * NN + q]);
        out[(p + 1) * NN + q] = fmaf(ty, scale, hf * W[(p + 1) * NN + q]);
    }
}

// fallback epilogue when S was atomically accumulated in d_out
__global__ void finalize_at(const float* __restrict__ hfac, const float* __restrict__ W,
                            float* __restrict__ out)
{
    const int i = (blockIdx.x * 256 + threadIdx.x) * 2;
    const int q = i & 127;
    const float scale = (float)((0.005 - 0.00525) / (double)(BB * TT));
    float2 s = *(const float2*)(out + i);
    float2 w = *(const float2*)(W + i);
    float2 o;
    o.x = fmaf(s.x, scale, hfac[q] * w.x);
    o.y = fmaf(s.y, scale, hfac[q + 1] * w.y);
    *(float2*)(out + i) = o;
}

extern "C" void kernel_launch(void* const* d_in, const int* in_sizes, int n_in,
                              void* d_out, int out_size, void* d_ws, size_t ws_size,
                              hipStream_t stream)
{
    const float* pre  = (const float*)d_in[0];
    const float* post = (const float*)d_in[1];
    const float* W    = (const float*)d_in[2];
    const int*   dtp  = (const int*)d_in[3];
    float* out = (float*)d_out;

    const size_t part_bytes  = (size_t)NBLK * SLOTS * sizeof(unsigned int); // 16 MiB
    const size_t wpost_bytes = (size_t)NBLK * NN * sizeof(float);           // 256 KiB
    const size_t need = part_bytes + wpost_bytes + NN * sizeof(float);

    if (ws_size >= need) {
        unsigned int* part = (unsigned int*)d_ws;
        float* wpost       = (float*)((char*)d_ws + part_bytes);
        float* hfac        = (float*)((char*)d_ws + part_bytes + wpost_bytes);
        hipLaunchKernelGGL((stdp_main<false>), dim3(NBLK), dim3(512), 0, stream,
                           pre, post, dtp, part, wpost, (float*)nullptr);
        hipLaunchKernelGGL(hfac_kernel, dim3(NN), dim3(64), 0, stream, wpost, dtp, hfac, NBLK);
        hipLaunchKernelGGL(finalize_ws, dim3(SLOTS / 64), dim3(512), 0, stream, part, hfac, W, out);
    } else {
        // atomic fallback: needs only ~1 KiB of workspace
        float* wpost = (float*)d_ws;
        float* hfac  = wpost + NN;
        hipMemsetAsync(d_out, 0, OUTN * sizeof(float), stream);
        hipMemsetAsync(wpost, 0, NN * sizeof(float), stream);
        hipLaunchKernelGGL((stdp_main<true>), dim3(NBLK), dim3(512), 0, stream,
                           pre, post, dtp, (unsigned int*)nullptr, wpost, out);
        hipLaunchKernelGGL(hfac_kernel, dim3(NN), dim3(64), 0, stream, wpost, dtp, hfac, 1);
        hipLaunchKernelGGL(finalize_at, dim3(OUTN / 512), dim3(256), 0, stream, hfac, W, out);
    }
}